// Round 2
// baseline (7239.050 us; speedup 1.0000x reference)
//
#include <hip/hip_runtime.h>
#include <hip/hip_bf16.h>

#define B_   16384
#define F_   18
#define V_   100000
#define E_   64
#define IN0_ 1152

struct IMap { int v[16]; };

// ---------------- embedding gather: feat[b, f*64+e] = emb[f, x[b,f], e] ----------------
__global__ void gather_kernel(const int* __restrict__ x, const float* __restrict__ emb,
                              float* __restrict__ feat) {
    int i = blockIdx.x * 256 + threadIdx.x;           // chunk over B*F*16 (float4 chunks)
    if (i >= B_ * F_ * 16) return;
    int ch = i & 15;
    int f  = (i >> 4) % F_;
    int b  = i / (F_ * 16);
    int v  = x[b * F_ + f];
    float4 src = *reinterpret_cast<const float4*>(emb + ((size_t)f * V_ + v) * E_ + ch * 4);
    *reinterpret_cast<float4*>(feat + (size_t)b * IN0_ + f * E_ + ch * 4) = src;
}

// ---------------- fp32 GEMM, 128x128 tile, BK=16, 8x8 microtile, double-buffered ----------------
// C[z][B,N] = A_z[B,K] @ W[map[z]][K,N] + bias[map[z]]. Requires K%16==0, N%128==0, M%128==0.
__launch_bounds__(256)
__global__ void gemm_bias128(const float* __restrict__ A, long strideA,
                             const float* __restrict__ W, const float* __restrict__ bias,
                             float* __restrict__ C, int K, int N, IMap map) {
    __shared__ float sA[2][16][132];   // [buf][k][row], 132 pad: conflict-light, 16B-aligned rows
    __shared__ float sB[2][16][128];   // [buf][k][col]
    const int z = blockIdx.z;
    const float* Az = A + (size_t)z * strideA;
    const float* Wz = W + (size_t)map.v[z] * K * N;
    const float* bz = bias + (size_t)map.v[z] * N;
    float* Cz = C + (size_t)z * (size_t)B_ * N;

    const int tid = threadIdx.x;
    const int m0 = blockIdx.y * 128, n0 = blockIdx.x * 128;
    const int tx = tid & 15, ty = tid >> 4;           // 16x16 threads, 8x8 micro each
    // A-load: each thread one 32B chunk: row 0..127, k-offset 0 or 8
    const int ar = tid >> 1, ak = (tid & 1) * 8;
    // B-load: two iterations, each thread a float4: k = (tid>>5)+8*it, col = (tid&31)*4
    const int bk = tid >> 5, bc = (tid & 31) * 4;

    float4 pa0, pa1, pb0, pb1;
    float acc[8][8] = {};

#define LOAD_TILE(k0)  do { \
        const float* ap = Az + (size_t)(m0 + ar) * K + (k0) + ak; \
        pa0 = *reinterpret_cast<const float4*>(ap); \
        pa1 = *reinterpret_cast<const float4*>(ap + 4); \
        pb0 = *reinterpret_cast<const float4*>(Wz + (size_t)((k0) + bk) * N + n0 + bc); \
        pb1 = *reinterpret_cast<const float4*>(Wz + (size_t)((k0) + bk + 8) * N + n0 + bc); \
    } while (0)

#define STORE_TILE(buf) do { \
        sA[buf][ak + 0][ar] = pa0.x; sA[buf][ak + 1][ar] = pa0.y; \
        sA[buf][ak + 2][ar] = pa0.z; sA[buf][ak + 3][ar] = pa0.w; \
        sA[buf][ak + 4][ar] = pa1.x; sA[buf][ak + 5][ar] = pa1.y; \
        sA[buf][ak + 6][ar] = pa1.z; sA[buf][ak + 7][ar] = pa1.w; \
        *reinterpret_cast<float4*>(&sB[buf][bk][bc])     = pb0; \
        *reinterpret_cast<float4*>(&sB[buf][bk + 8][bc]) = pb1; \
    } while (0)

    const int ntk = K >> 4;
    LOAD_TILE(0);
    STORE_TILE(0);
    __syncthreads();

    for (int kt = 0; kt < ntk; ++kt) {
        const int cur = kt & 1;
        if (kt + 1 < ntk) LOAD_TILE((kt + 1) << 4);
        #pragma unroll
        for (int kk = 0; kk < 16; ++kk) {
            float4 av0 = *reinterpret_cast<const float4*>(&sA[cur][kk][ty * 8]);
            float4 av1 = *reinterpret_cast<const float4*>(&sA[cur][kk][ty * 8 + 4]);
            float4 bv0 = *reinterpret_cast<const float4*>(&sB[cur][kk][tx * 8]);
            float4 bv1 = *reinterpret_cast<const float4*>(&sB[cur][kk][tx * 8 + 4]);
            float a[8] = {av0.x, av0.y, av0.z, av0.w, av1.x, av1.y, av1.z, av1.w};
            float b[8] = {bv0.x, bv0.y, bv0.z, bv0.w, bv1.x, bv1.y, bv1.z, bv1.w};
            #pragma unroll
            for (int i = 0; i < 8; ++i)
                #pragma unroll
                for (int j = 0; j < 8; ++j)
                    acc[i][j] += a[i] * b[j];
        }
        if (kt + 1 < ntk) STORE_TILE((kt + 1) & 1);
        __syncthreads();
    }
#undef LOAD_TILE
#undef STORE_TILE

    float4 bvl = *reinterpret_cast<const float4*>(bz + n0 + tx * 8);
    float4 bvh = *reinterpret_cast<const float4*>(bz + n0 + tx * 8 + 4);
    #pragma unroll
    for (int i = 0; i < 8; ++i) {
        float* cp = Cz + (size_t)(m0 + ty * 8 + i) * N + n0 + tx * 8;
        float4 o0 = { acc[i][0] + bvl.x, acc[i][1] + bvl.y, acc[i][2] + bvl.z, acc[i][3] + bvl.w };
        float4 o1 = { acc[i][4] + bvh.x, acc[i][5] + bvh.y, acc[i][6] + bvh.z, acc[i][7] + bvh.w };
        *reinterpret_cast<float4*>(cp)     = o0;
        *reinterpret_cast<float4*>(cp + 4) = o1;
    }
}

// ---------------- fp32 GEMM 64x64 tile (small-N fallback: tower layer N=64) ----------------
__launch_bounds__(256)
__global__ void gemm_bias(const float* __restrict__ A, long strideA,
                          const float* __restrict__ W, const float* __restrict__ bias,
                          float* __restrict__ C, int K, int N, IMap map) {
    __shared__ float sA[16][68];
    __shared__ float sB[16][64];
    const int z = blockIdx.z;
    const float* Az = A + (size_t)z * strideA;
    const float* Wz = W + (size_t)map.v[z] * K * N;
    const float* bz = bias + (size_t)map.v[z] * N;
    float* Cz = C + (size_t)z * (size_t)B_ * N;

    const int tid = threadIdx.x;
    const int m0 = blockIdx.y * 64, n0 = blockIdx.x * 64;
    const int tx = tid & 15, ty = tid >> 4;
    const int lr  = tid >> 2,  lk  = (tid & 3) * 4;
    const int lbk = tid >> 4,  lbc = (tid & 15) * 4;

    float acc[4][4] = {};
    for (int k0 = 0; k0 < K; k0 += 16) {
        float4 a4 = *reinterpret_cast<const float4*>(Az + (size_t)(m0 + lr) * K + k0 + lk);
        float4 b4 = *reinterpret_cast<const float4*>(Wz + (size_t)(k0 + lbk) * N + n0 + lbc);
        __syncthreads();
        sA[lk + 0][lr] = a4.x; sA[lk + 1][lr] = a4.y;
        sA[lk + 2][lr] = a4.z; sA[lk + 3][lr] = a4.w;
        *reinterpret_cast<float4*>(&sB[lbk][lbc]) = b4;
        __syncthreads();
        #pragma unroll
        for (int kk = 0; kk < 16; ++kk) {
            float4 av = *reinterpret_cast<const float4*>(&sA[kk][ty * 4]);
            float4 bv = *reinterpret_cast<const float4*>(&sB[kk][tx * 4]);
            float a[4] = {av.x, av.y, av.z, av.w};
            float b[4] = {bv.x, bv.y, bv.z, bv.w};
            #pragma unroll
            for (int i = 0; i < 4; ++i)
                #pragma unroll
                for (int j = 0; j < 4; ++j)
                    acc[i][j] += a[i] * b[j];
        }
    }
    float4 bv = *reinterpret_cast<const float4*>(bz + n0 + tx * 4);
    #pragma unroll
    for (int i = 0; i < 4; ++i) {
        float4 o = { acc[i][0] + bv.x, acc[i][1] + bv.y, acc[i][2] + bv.z, acc[i][3] + bv.w };
        *reinterpret_cast<float4*>(Cz + (size_t)(m0 + ty * 4 + i) * N + n0 + tx * 4) = o;
    }
}

// ---------------- BN batch stats (training mode): per (slot, column) over B rows ----------------
__global__ void bn_sum(const float* __restrict__ H, int N, int rows,
                       float* __restrict__ sumb, float* __restrict__ sumsqb) {
    int c = blockIdx.x * 256 + threadIdx.x;
    int z = blockIdx.z;
    if (c >= N) return;
    const float* p = H + (size_t)z * B_ * N + (size_t)blockIdx.y * rows * N + c;
    float s = 0.f, q = 0.f;
    for (int r = 0; r < rows; ++r) { float v = p[(size_t)r * N]; s += v; q += v * v; }
    atomicAdd(&sumb[z * N + c], s);
    atomicAdd(&sumsqb[z * N + c], q);
}

__global__ void bn_fin(const float* __restrict__ sumb, const float* __restrict__ sumsqb,
                       int total, float* __restrict__ meanb, float* __restrict__ rstdb) {
    int i = blockIdx.x * 256 + threadIdx.x;
    if (i >= total) return;
    float m = sumb[i] * (1.f / B_);
    float v = sumsqb[i] * (1.f / B_) - m * m;
    meanb[i] = m;
    rstdb[i] = rsqrtf(v + 1e-5f);
}

// ---------------- gate logits: logits[b][t][e] = A_t[b,:] . gw[t][:,e] + gb[t][e] ----------------
__global__ void gate_logits(const float* __restrict__ A0, const float* __restrict__ A1, int K,
                            const float* __restrict__ gw, const float* __restrict__ gb,
                            float* __restrict__ logits) {
    int i = blockIdx.x * 256 + threadIdx.x;           // over B*16
    if (i >= B_ * 16) return;
    int e = i & 7, t = (i >> 3) & 1, b = i >> 4;
    const float* A = (t == 0 ? A0 : A1) + (size_t)b * K;
    const float* w = gw + (size_t)t * K * 8;
    float acc = gb[t * 8 + e];
    for (int k = 0; k < K; k += 4) {
        float4 a = *reinterpret_cast<const float4*>(A + k);
        acc += a.x * w[(k + 0) * 8 + e] + a.y * w[(k + 1) * 8 + e]
             + a.z * w[(k + 2) * 8 + e] + a.w * w[(k + 3) * 8 + e];
    }
    logits[i] = acc;
}

// ---------------- mix: out[b,c] = sum_e softmax(logits)[e] * relu(BN(H[slot_e][b,c])) ----------------
__global__ void mix_kernel(const float* __restrict__ H, long Hstride, int N,
                           const float* __restrict__ logits, int t,
                           const float* __restrict__ meanb, const float* __restrict__ rstdb,
                           const float* __restrict__ g, const float* __restrict__ bt,
                           IMap slotmap, IMap gmap, float* __restrict__ out) {
    int b = blockIdx.x;
    float p[8];
    float mx = -1e30f;
    #pragma unroll
    for (int e = 0; e < 8; ++e) { p[e] = logits[b * 16 + t * 8 + e]; mx = fmaxf(mx, p[e]); }
    float s = 0.f;
    #pragma unroll
    for (int e = 0; e < 8; ++e) { p[e] = expf(p[e] - mx); s += p[e]; }
    float inv = 1.f / s;
    #pragma unroll
    for (int e = 0; e < 8; ++e) p[e] *= inv;
    for (int c = threadIdx.x; c < N; c += 256) {
        float acc = 0.f;
        #pragma unroll
        for (int e = 0; e < 8; ++e) {
            int sl = slotmap.v[e], gi = gmap.v[e];
            float v = H[(size_t)sl * Hstride + (size_t)b * N + c];
            v = (v - meanb[sl * N + c]) * rstdb[sl * N + c] * g[gi * N + c] + bt[gi * N + c];
            acc += p[e] * fmaxf(v, 0.f);
        }
        out[(size_t)b * N + c] = acc;
    }
}

// ---------------- in-place BN+ReLU (towers) ----------------
__global__ void bn_relu(float* __restrict__ T, int N,
                        const float* __restrict__ meanb, const float* __restrict__ rstdb,
                        const float* __restrict__ g, const float* __restrict__ bt, int total) {
    int i = blockIdx.x * 256 + threadIdx.x;
    if (i >= total) return;
    int z = i / (B_ * N);
    int c = i % N;
    int idx = z * N + c;
    float v = T[i];
    v = (v - meanb[idx]) * rstdb[idx] * g[idx] + bt[idx];
    T[i] = fmaxf(v, 0.f);
}

// ---------------- final: out[t*B+b] = sigmoid(T1[t][b,:] . tow[t] + tob[t]) ----------------
__global__ void final_kernel(const float* __restrict__ T1, const float* __restrict__ tow,
                             const float* __restrict__ tob, float* __restrict__ out) {
    int r = blockIdx.x * 4 + (threadIdx.x >> 6);      // row over 2*B (t*B+b)
    int lane = threadIdx.x & 63;
    int t = r >> 14;
    float v = T1[(size_t)r * 64 + lane] * tow[t * 64 + lane];
    #pragma unroll
    for (int off = 32; off > 0; off >>= 1) v += __shfl_xor(v, off);
    if (lane == 0) out[r] = 1.f / (1.f + expf(-(v + tob[t])));
}

extern "C" void kernel_launch(void* const* d_in, const int* in_sizes, int n_in,
                              void* d_out, int out_size, void* d_ws, size_t ws_size,
                              hipStream_t stream) {
    const int*   x    = (const int*)  d_in[0];
    const float* emb  = (const float*)d_in[1];
    const float* ew0  = (const float*)d_in[2];
    const float* eb0  = (const float*)d_in[3];
    const float* eg0  = (const float*)d_in[4];
    const float* ebt0 = (const float*)d_in[5];
    const float* gw0  = (const float*)d_in[6];
    const float* gb0  = (const float*)d_in[7];
    // d_in[8] gsw0, d_in[9] gsb0: unused (shared stream pruned)
    const float* ew1  = (const float*)d_in[10];
    const float* eb1  = (const float*)d_in[11];
    const float* eg1  = (const float*)d_in[12];
    const float* ebt1 = (const float*)d_in[13];
    const float* gw1  = (const float*)d_in[14];
    const float* gb1  = (const float*)d_in[15];
    // d_in[16] gsw1, d_in[17] gsb1: unused
    const float* tw0  = (const float*)d_in[18];
    const float* tb0  = (const float*)d_in[19];
    const float* tg0  = (const float*)d_in[20];
    const float* tbt0 = (const float*)d_in[21];
    const float* tw1  = (const float*)d_in[22];
    const float* tb1  = (const float*)d_in[23];
    const float* tg1  = (const float*)d_in[24];
    const float* tbt1 = (const float*)d_in[25];
    const float* tow  = (const float*)d_in[26];
    const float* tob  = (const float*)d_in[27];
    float* out = (float*)d_out;

    // workspace layout (floats)
    float* ws     = (float*)d_ws;
    float* feat   = ws;                                  // B*1152
    float* H      = feat + (size_t)B_ * IN0_;            // 12*B*512 (reused: 16*B*256)
    float* X      = H + (size_t)12 * B_ * 512;           // 2*B*512
    float* Y      = X + (size_t)2 * B_ * 512;            // 2*B*256
    float* T0     = Y + (size_t)2 * B_ * 256;            // 2*B*128
    float* T1     = T0 + (size_t)2 * B_ * 128;           // 2*B*64
    float* logits = T1 + (size_t)2 * B_ * 64;            // B*16
    float* sumb   = logits + (size_t)B_ * 16;            // 8192
    float* sumsqb = sumb + 8192;
    float* meanb  = sumsqb + 8192;
    float* rstdb  = meanb + 8192;

    IMap idm, map_t0, map_t1, sl07, sl815, m01;
    for (int i = 0; i < 16; ++i) { idm.v[i] = i; sl07.v[i] = i; m01.v[i] = i & 1; }
    int a0[8] = {0,1,2,3,8,9,10,11}, a1[8] = {4,5,6,7,8,9,10,11};
    for (int i = 0; i < 8; ++i) { map_t0.v[i] = a0[i]; map_t1.v[i] = a1[i]; sl815.v[i] = 8 + i; }
    m01.v[0] = 0; m01.v[1] = 1;

    // 1) embedding gather
    gather_kernel<<<(B_ * F_ * 16 + 255) / 256, 256, 0, stream>>>(x, emb, feat);

    // 2) layer 0: 12 expert GEMMs (deduped across streams; all share input feat)
    gemm_bias128<<<dim3(512 / 128, B_ / 128, 12), 256, 0, stream>>>(feat, 0, ew0, eb0, H, IN0_, 512, idm);
    hipMemsetAsync(sumb,   0, 12 * 512 * sizeof(float), stream);
    hipMemsetAsync(sumsqb, 0, 12 * 512 * sizeof(float), stream);
    bn_sum<<<dim3(2, 32, 12), 256, 0, stream>>>(H, 512, B_ / 32, sumb, sumsqb);
    bn_fin<<<(12 * 512 + 255) / 256, 256, 0, stream>>>(sumb, sumsqb, 12 * 512, meanb, rstdb);
    gate_logits<<<(B_ * 16 + 255) / 256, 256, 0, stream>>>(feat, feat, IN0_, gw0, gb0, logits);
    mix_kernel<<<B_, 256, 0, stream>>>(H, (long)B_ * 512, 512, logits, 0, meanb, rstdb,
                                       eg0, ebt0, map_t0, map_t0, X);
    mix_kernel<<<B_, 256, 0, stream>>>(H, (long)B_ * 512, 512, logits, 1, meanb, rstdb,
                                       eg0, ebt0, map_t1, map_t1, X + (size_t)B_ * 512);

    // 3) layer 1: 16 expert GEMMs (stream 2 pruned: its output is never consumed)
    gemm_bias128<<<dim3(256 / 128, B_ / 128, 8), 256, 0, stream>>>(X, 0, ew1, eb1, H, 512, 256, map_t0);
    gemm_bias128<<<dim3(256 / 128, B_ / 128, 8), 256, 0, stream>>>(X + (size_t)B_ * 512, 0, ew1, eb1,
                                                                   H + (size_t)8 * B_ * 256, 512, 256, map_t1);
    hipMemsetAsync(sumb,   0, 16 * 256 * sizeof(float), stream);
    hipMemsetAsync(sumsqb, 0, 16 * 256 * sizeof(float), stream);
    bn_sum<<<dim3(1, 32, 16), 256, 0, stream>>>(H, 256, B_ / 32, sumb, sumsqb);
    bn_fin<<<(16 * 256 + 255) / 256, 256, 0, stream>>>(sumb, sumsqb, 16 * 256, meanb, rstdb);
    gate_logits<<<(B_ * 16 + 255) / 256, 256, 0, stream>>>(X, X + (size_t)B_ * 512, 512, gw1, gb1, logits);
    mix_kernel<<<B_, 256, 0, stream>>>(H, (long)B_ * 256, 256, logits, 0, meanb, rstdb,
                                       eg1, ebt1, sl07, map_t0, Y);
    mix_kernel<<<B_, 256, 0, stream>>>(H, (long)B_ * 256, 256, logits, 1, meanb, rstdb,
                                       eg1, ebt1, sl815, map_t1, Y + (size_t)B_ * 256);

    // 4) towers (batched over the 2 tasks via blockIdx.z)
    gemm_bias128<<<dim3(1, B_ / 128, 2), 256, 0, stream>>>(Y, (long)B_ * 256, tw0, tb0, T0, 256, 128, m01);
    hipMemsetAsync(sumb,   0, 2 * 128 * sizeof(float), stream);
    hipMemsetAsync(sumsqb, 0, 2 * 128 * sizeof(float), stream);
    bn_sum<<<dim3(1, 32, 2), 256, 0, stream>>>(T0, 128, B_ / 32, sumb, sumsqb);
    bn_fin<<<1, 256, 0, stream>>>(sumb, sumsqb, 2 * 128, meanb, rstdb);
    bn_relu<<<(2 * B_ * 128 + 255) / 256, 256, 0, stream>>>(T0, 128, meanb, rstdb, tg0, tbt0, 2 * B_ * 128);

    gemm_bias<<<dim3(1, B_ / 64, 2), 256, 0, stream>>>(T0, (long)B_ * 128, tw1, tb1, T1, 128, 64, m01);
    hipMemsetAsync(sumb,   0, 2 * 64 * sizeof(float), stream);
    hipMemsetAsync(sumsqb, 0, 2 * 64 * sizeof(float), stream);
    bn_sum<<<dim3(1, 32, 2), 256, 0, stream>>>(T1, 64, B_ / 32, sumb, sumsqb);
    bn_fin<<<1, 256, 0, stream>>>(sumb, sumsqb, 2 * 64, meanb, rstdb);
    bn_relu<<<(2 * B_ * 64 + 255) / 256, 256, 0, stream>>>(T1, 64, meanb, rstdb, tg1, tbt1, 2 * B_ * 64);

    final_kernel<<<2 * B_ / 4, 256, 0, stream>>>(T1, tow, tob, out);
}

// Round 3
// 3084.172 us; speedup vs baseline: 2.3472x; 2.3472x over previous
//
#include <hip/hip_runtime.h>
#include <hip/hip_bf16.h>

#define B_   16384
#define F_   18
#define V_   100000
#define E_   64
#define IN0_ 1152

typedef unsigned short u16;
typedef __attribute__((ext_vector_type(4))) unsigned short u16x4;
typedef __attribute__((ext_vector_type(8))) short short8;   // 8 bf16 (4 VGPRs)
typedef __attribute__((ext_vector_type(4))) float f32x4;

struct IMap { int v[16]; };

__device__ inline u16 f2bf(float x) {                 // RNE fp32 -> bf16 bits
    unsigned u = __float_as_uint(x);
    return (u16)((u + 0x7FFFu + ((u >> 16) & 1u)) >> 16);
}
__device__ inline float bf2f(u16 h) { return __uint_as_float(((unsigned)h) << 16); }

#define GLL(gp, lp) __builtin_amdgcn_global_load_lds( \
        (const __attribute__((address_space(1))) void*)(gp), \
        (__attribute__((address_space(3))) void*)(lp), 16, 0, 0)

// ---------------- embedding gather -> split bf16 planes ----------------
__global__ void gather_kernel(const int* __restrict__ x, const float* __restrict__ emb,
                              u16* __restrict__ fH, u16* __restrict__ fL) {
    int i = blockIdx.x * 256 + threadIdx.x;           // over B*F*16 float4-chunks
    if (i >= B_ * F_ * 16) return;
    int ch = i & 15;
    int f  = (i >> 4) % F_;
    int b  = i / (F_ * 16);
    int v  = x[b * F_ + f];
    float4 s = *reinterpret_cast<const float4*>(emb + ((size_t)f * V_ + v) * E_ + ch * 4);
    size_t off = (size_t)b * IN0_ + f * E_ + ch * 4;
    u16x4 h, l;
    float sv[4] = {s.x, s.y, s.z, s.w};
    #pragma unroll
    for (int j = 0; j < 4; ++j) {
        u16 hh = f2bf(sv[j]); h[j] = hh; l[j] = f2bf(sv[j] - bf2f(hh));
    }
    *reinterpret_cast<u16x4*>(fH + off) = h;
    *reinterpret_cast<u16x4*>(fL + off) = l;
}

// ---------------- W [E,K,N] fp32 -> W^T [E,N,K] split bf16 planes ----------------
__global__ void wt_conv(const float* __restrict__ W, int K, int N,
                        u16* __restrict__ TH, u16* __restrict__ TL) {
    __shared__ float sT[32][33];
    int e = blockIdx.z;
    const float* We = W + (size_t)e * K * N;
    u16* THe = TH + (size_t)e * N * K;
    u16* TLe = TL + (size_t)e * N * K;
    int n0 = blockIdx.x * 32, k0 = blockIdx.y * 32;
    int tx = threadIdx.x & 31, ty = threadIdx.x >> 5;     // ty 0..7
    #pragma unroll
    for (int r = 0; r < 4; ++r) {
        int k = ty + r * 8;
        sT[k][tx] = We[(size_t)(k0 + k) * N + n0 + tx];
    }
    __syncthreads();
    #pragma unroll
    for (int r = 0; r < 4; ++r) {
        int n = ty + r * 8;
        float v = sT[tx][n];
        u16 h = f2bf(v);
        THe[(size_t)(n0 + n) * K + k0 + tx] = h;
        TLe[(size_t)(n0 + n) * K + k0 + tx] = f2bf(v - bf2f(h));
    }
}

// ---------------- split-bf16 MFMA GEMM: C[z] = (Ah+Al) @ (Bh+Bl)^T + bias ----------------
// A planes [M,K] bf16, B^T planes [N,K] bf16, both K-contiguous. 128x128 tile, BK=32,
// 4 waves each 64x64 (4x4 of 16x16x32 fragments). m97-structure staging via global_load_lds.
__launch_bounds__(256)
__global__ void gemm_mfma(const u16* __restrict__ AH, const u16* __restrict__ AL, long strideA,
                          const u16* __restrict__ BTH, const u16* __restrict__ BTL,
                          const float* __restrict__ bias, float* __restrict__ C,
                          int K, int N, IMap map) {
    __shared__ u16 sAH[128 * 32], sAL[128 * 32], sBH[128 * 32], sBL[128 * 32];
    const int z = blockIdx.z;
    const u16* AHz = AH + (size_t)z * strideA;
    const u16* ALz = AL + (size_t)z * strideA;
    const u16* BHz = BTH + (size_t)map.v[z] * N * K;
    const u16* BLz = BTL + (size_t)map.v[z] * N * K;
    const float* bz = bias + (size_t)map.v[z] * N;
    float* Cz = C + (size_t)z * (size_t)B_ * N;

    const int tid = threadIdx.x;
    const int lane = tid & 63, w = tid >> 6;
    const int wr = w >> 1, wc = w & 1;                 // wave tile origin (64x64)
    const int m0 = blockIdx.y * 128, n0 = blockIdx.x * 128;
    const int fr = lane & 15, kg = lane >> 4;          // fragment row/col, k-group

    f32x4 acc[4][4];
    #pragma unroll
    for (int i = 0; i < 4; ++i)
        #pragma unroll
        for (int j = 0; j < 4; ++j) acc[i][j] = (f32x4){0.f, 0.f, 0.f, 0.f};

    const int ntk = K >> 5;
    for (int kt = 0; kt < ntk; ++kt) {
        const int k0 = kt << 5;
        __syncthreads();                               // all waves done with prev tile
        #pragma unroll
        for (int s = 0; s < 2; ++s) {
            const int ci  = tid + (s << 8);            // chunk 0..511 (16B each)
            const int row = ci >> 2;
            const int ko  = (ci & 3) << 3;             // ushort offset in row
            const int lb  = (((tid >> 6) << 6) + (s << 8)) * 8;  // wave-uniform LDS ushort base
            GLL(AHz + (size_t)(m0 + row) * K + k0 + ko, sAH + lb);
            GLL(ALz + (size_t)(m0 + row) * K + k0 + ko, sAL + lb);
            GLL(BHz + (size_t)(n0 + row) * K + k0 + ko, sBH + lb);
            GLL(BLz + (size_t)(n0 + row) * K + k0 + ko, sBL + lb);
        }
        __syncthreads();                               // compiler drains vmcnt(0) before barrier

        short8 afh[4], afl[4], bfh[4], bfl[4];
        #pragma unroll
        for (int i = 0; i < 4; ++i) {
            const int ar = (wr * 64 + i * 16 + fr) * 32 + kg * 8;
            afh[i] = *reinterpret_cast<const short8*>(&sAH[ar]);
            afl[i] = *reinterpret_cast<const short8*>(&sAL[ar]);
            const int br = (wc * 64 + i * 16 + fr) * 32 + kg * 8;
            bfh[i] = *reinterpret_cast<const short8*>(&sBH[br]);
            bfl[i] = *reinterpret_cast<const short8*>(&sBL[br]);
        }
        #pragma unroll
        for (int i = 0; i < 4; ++i)
            #pragma unroll
            for (int j = 0; j < 4; ++j) {
                acc[i][j] = __builtin_amdgcn_mfma_f32_16x16x32_bf16(afh[i], bfh[j], acc[i][j], 0, 0, 0);
                acc[i][j] = __builtin_amdgcn_mfma_f32_16x16x32_bf16(afh[i], bfl[j], acc[i][j], 0, 0, 0);
                acc[i][j] = __builtin_amdgcn_mfma_f32_16x16x32_bf16(afl[i], bfh[j], acc[i][j], 0, 0, 0);
            }
    }

    // epilogue: C/D layout col=lane&15, row=(lane>>4)*4+reg  [verified m89/m91]
    const int orow = (lane >> 4) * 4;
    #pragma unroll
    for (int i = 0; i < 4; ++i)
        #pragma unroll
        for (int j = 0; j < 4; ++j) {
            const int row = m0 + wr * 64 + i * 16 + orow;
            const int col = n0 + wc * 64 + j * 16 + fr;
            const float bv = bz[col];
            #pragma unroll
            for (int r = 0; r < 4; ++r)
                Cz[(size_t)(row + r) * N + col] = acc[i][j][r] + bv;
        }
}

// ---------------- fp32 GEMM 128x128 (towers, K%16==0, N%128==0) ----------------
__launch_bounds__(256)
__global__ void gemm_bias128(const float* __restrict__ A, long strideA,
                             const float* __restrict__ W, const float* __restrict__ bias,
                             float* __restrict__ C, int K, int N, IMap map) {
    __shared__ float sA[2][16][132];
    __shared__ float sB[2][16][128];
    const int z = blockIdx.z;
    const float* Az = A + (size_t)z * strideA;
    const float* Wz = W + (size_t)map.v[z] * K * N;
    const float* bz = bias + (size_t)map.v[z] * N;
    float* Cz = C + (size_t)z * (size_t)B_ * N;

    const int tid = threadIdx.x;
    const int m0 = blockIdx.y * 128, n0 = blockIdx.x * 128;
    const int tx = tid & 15, ty = tid >> 4;
    const int ar = tid >> 1, ak = (tid & 1) * 8;
    const int bk = tid >> 5, bc = (tid & 31) * 4;

    float4 pa0, pa1, pb0, pb1;
    float acc[8][8] = {};

#define LOAD_TILE(k0)  do { \
        const float* ap = Az + (size_t)(m0 + ar) * K + (k0) + ak; \
        pa0 = *reinterpret_cast<const float4*>(ap); \
        pa1 = *reinterpret_cast<const float4*>(ap + 4); \
        pb0 = *reinterpret_cast<const float4*>(Wz + (size_t)((k0) + bk) * N + n0 + bc); \
        pb1 = *reinterpret_cast<const float4*>(Wz + (size_t)((k0) + bk + 8) * N + n0 + bc); \
    } while (0)
#define STORE_TILE(buf) do { \
        sA[buf][ak + 0][ar] = pa0.x; sA[buf][ak + 1][ar] = pa0.y; \
        sA[buf][ak + 2][ar] = pa0.z; sA[buf][ak + 3][ar] = pa0.w; \
        sA[buf][ak + 4][ar] = pa1.x; sA[buf][ak + 5][ar] = pa1.y; \
        sA[buf][ak + 6][ar] = pa1.z; sA[buf][ak + 7][ar] = pa1.w; \
        *reinterpret_cast<float4*>(&sB[buf][bk][bc])     = pb0; \
        *reinterpret_cast<float4*>(&sB[buf][bk + 8][bc]) = pb1; \
    } while (0)

    const int ntk = K >> 4;
    LOAD_TILE(0);
    STORE_TILE(0);
    __syncthreads();
    for (int kt = 0; kt < ntk; ++kt) {
        const int cur = kt & 1;
        if (kt + 1 < ntk) LOAD_TILE((kt + 1) << 4);
        #pragma unroll
        for (int kk = 0; kk < 16; ++kk) {
            float4 av0 = *reinterpret_cast<const float4*>(&sA[cur][kk][ty * 8]);
            float4 av1 = *reinterpret_cast<const float4*>(&sA[cur][kk][ty * 8 + 4]);
            float4 bv0 = *reinterpret_cast<const float4*>(&sB[cur][kk][tx * 8]);
            float4 bv1 = *reinterpret_cast<const float4*>(&sB[cur][kk][tx * 8 + 4]);
            float a[8] = {av0.x, av0.y, av0.z, av0.w, av1.x, av1.y, av1.z, av1.w};
            float b[8] = {bv0.x, bv0.y, bv0.z, bv0.w, bv1.x, bv1.y, bv1.z, bv1.w};
            #pragma unroll
            for (int i = 0; i < 8; ++i)
                #pragma unroll
                for (int j = 0; j < 8; ++j)
                    acc[i][j] += a[i] * b[j];
        }
        if (kt + 1 < ntk) STORE_TILE((kt + 1) & 1);
        __syncthreads();
    }
#undef LOAD_TILE
#undef STORE_TILE
    float4 bvl = *reinterpret_cast<const float4*>(bz + n0 + tx * 8);
    float4 bvh = *reinterpret_cast<const float4*>(bz + n0 + tx * 8 + 4);
    #pragma unroll
    for (int i = 0; i < 8; ++i) {
        float* cp = Cz + (size_t)(m0 + ty * 8 + i) * N + n0 + tx * 8;
        float4 o0 = { acc[i][0] + bvl.x, acc[i][1] + bvl.y, acc[i][2] + bvl.z, acc[i][3] + bvl.w };
        float4 o1 = { acc[i][4] + bvh.x, acc[i][5] + bvh.y, acc[i][6] + bvh.z, acc[i][7] + bvh.w };
        *reinterpret_cast<float4*>(cp)     = o0;
        *reinterpret_cast<float4*>(cp + 4) = o1;
    }
}

// ---------------- fp32 GEMM 64x64 (tower layer N=64) ----------------
__launch_bounds__(256)
__global__ void gemm_bias(const float* __restrict__ A, long strideA,
                          const float* __restrict__ W, const float* __restrict__ bias,
                          float* __restrict__ C, int K, int N, IMap map) {
    __shared__ float sA[16][68];
    __shared__ float sB[16][64];
    const int z = blockIdx.z;
    const float* Az = A + (size_t)z * strideA;
    const float* Wz = W + (size_t)map.v[z] * K * N;
    const float* bz = bias + (size_t)map.v[z] * N;
    float* Cz = C + (size_t)z * (size_t)B_ * N;

    const int tid = threadIdx.x;
    const int m0 = blockIdx.y * 64, n0 = blockIdx.x * 64;
    const int tx = tid & 15, ty = tid >> 4;
    const int lr  = tid >> 2,  lk  = (tid & 3) * 4;
    const int lbk = tid >> 4,  lbc = (tid & 15) * 4;

    float acc[4][4] = {};
    for (int k0 = 0; k0 < K; k0 += 16) {
        float4 a4 = *reinterpret_cast<const float4*>(Az + (size_t)(m0 + lr) * K + k0 + lk);
        float4 b4 = *reinterpret_cast<const float4*>(Wz + (size_t)(k0 + lbk) * N + n0 + lbc);
        __syncthreads();
        sA[lk + 0][lr] = a4.x; sA[lk + 1][lr] = a4.y;
        sA[lk + 2][lr] = a4.z; sA[lk + 3][lr] = a4.w;
        *reinterpret_cast<float4*>(&sB[lbk][lbc]) = b4;
        __syncthreads();
        #pragma unroll
        for (int kk = 0; kk < 16; ++kk) {
            float4 av = *reinterpret_cast<const float4*>(&sA[kk][ty * 4]);
            float4 bv = *reinterpret_cast<const float4*>(&sB[kk][tx * 4]);
            float a[4] = {av.x, av.y, av.z, av.w};
            float b[4] = {bv.x, bv.y, bv.z, bv.w};
            #pragma unroll
            for (int i = 0; i < 4; ++i)
                #pragma unroll
                for (int j = 0; j < 4; ++j)
                    acc[i][j] += a[i] * b[j];
        }
    }
    float4 bv = *reinterpret_cast<const float4*>(bz + n0 + tx * 4);
    #pragma unroll
    for (int i = 0; i < 4; ++i) {
        float4 o = { acc[i][0] + bv.x, acc[i][1] + bv.y, acc[i][2] + bv.z, acc[i][3] + bv.w };
        *reinterpret_cast<float4*>(Cz + (size_t)(m0 + ty * 4 + i) * N + n0 + tx * 4) = o;
    }
}

// ---------------- BN batch stats ----------------
__global__ void bn_sum(const float* __restrict__ H, int N, int rows,
                       float* __restrict__ sumb, float* __restrict__ sumsqb) {
    int c = blockIdx.x * 256 + threadIdx.x;
    int z = blockIdx.z;
    if (c >= N) return;
    const float* p = H + (size_t)z * B_ * N + (size_t)blockIdx.y * rows * N + c;
    float s = 0.f, q = 0.f;
    for (int r = 0; r < rows; ++r) { float v = p[(size_t)r * N]; s += v; q += v * v; }
    atomicAdd(&sumb[z * N + c], s);
    atomicAdd(&sumsqb[z * N + c], q);
}

__global__ void bn_fin(const float* __restrict__ sumb, const float* __restrict__ sumsqb,
                       int total, float* __restrict__ meanb, float* __restrict__ rstdb) {
    int i = blockIdx.x * 256 + threadIdx.x;
    if (i >= total) return;
    float m = sumb[i] * (1.f / B_);
    float v = sumsqb[i] * (1.f / B_) - m * m;
    meanb[i] = m;
    rstdb[i] = rsqrtf(v + 1e-5f);
}

// ---------------- gate logits: thread per (b,t), all 8 experts ----------------
__global__ void gate8(const u16* __restrict__ AH, const u16* __restrict__ AL, long tstride,
                      int K, const float* __restrict__ gw, const float* __restrict__ gb,
                      float* __restrict__ logits) {
    int i = blockIdx.x * 256 + threadIdx.x;           // over 2*B, b-major
    if (i >= 2 * B_) return;
    int t = i >> 14, b = i & (B_ - 1);
    const u16* ah = AH + (size_t)t * tstride + (size_t)b * K;
    const u16* al = AL + (size_t)t * tstride + (size_t)b * K;
    const float* w = gw + (size_t)t * K * 8;
    float acc[8];
    #pragma unroll
    for (int e = 0; e < 8; ++e) acc[e] = gb[t * 8 + e];
    for (int k = 0; k < K; k += 4) {
        u16x4 h4 = *reinterpret_cast<const u16x4*>(&ah[k]);
        u16x4 l4 = *reinterpret_cast<const u16x4*>(&al[k]);
        float a[4];
        #pragma unroll
        for (int j = 0; j < 4; ++j) a[j] = bf2f(h4[j]) + bf2f(l4[j]);
        #pragma unroll
        for (int e = 0; e < 8; ++e)
            acc[e] += a[0] * w[(k + 0) * 8 + e] + a[1] * w[(k + 1) * 8 + e]
                    + a[2] * w[(k + 2) * 8 + e] + a[3] * w[(k + 3) * 8 + e];
    }
    #pragma unroll
    for (int e = 0; e < 8; ++e) logits[b * 16 + t * 8 + e] = acc[e];
}

// ---------------- mix: out = sum_e softmax(logits)[e] * relu(BN(H[slot_e])) ----------------
__global__ void mix_kernel(const float* __restrict__ H, long Hstride, int N,
                           const float* __restrict__ logits, int t,
                           const float* __restrict__ meanb, const float* __restrict__ rstdb,
                           const float* __restrict__ g, const float* __restrict__ bt,
                           IMap slotmap, IMap gmap,
                           float* __restrict__ outF, u16* __restrict__ outH, u16* __restrict__ outL) {
    int b = blockIdx.x;
    float p[8];
    float mx = -1e30f;
    #pragma unroll
    for (int e = 0; e < 8; ++e) { p[e] = logits[b * 16 + t * 8 + e]; mx = fmaxf(mx, p[e]); }
    float s = 0.f;
    #pragma unroll
    for (int e = 0; e < 8; ++e) { p[e] = expf(p[e] - mx); s += p[e]; }
    float inv = 1.f / s;
    #pragma unroll
    for (int e = 0; e < 8; ++e) p[e] *= inv;
    for (int c = threadIdx.x; c < N; c += 256) {
        float acc = 0.f;
        #pragma unroll
        for (int e = 0; e < 8; ++e) {
            int sl = slotmap.v[e], gi = gmap.v[e];
            float v = H[(size_t)sl * Hstride + (size_t)b * N + c];
            v = (v - meanb[sl * N + c]) * rstdb[sl * N + c] * g[gi * N + c] + bt[gi * N + c];
            acc += p[e] * fmaxf(v, 0.f);
        }
        size_t oi = (size_t)b * N + c;
        if (outF) outF[oi] = acc;
        if (outH) {
            u16 h = f2bf(acc);
            outH[oi] = h;
            outL[oi] = f2bf(acc - bf2f(h));
        }
    }
}

// ---------------- in-place BN+ReLU (towers) ----------------
__global__ void bn_relu(float* __restrict__ T, int N,
                        const float* __restrict__ meanb, const float* __restrict__ rstdb,
                        const float* __restrict__ g, const float* __restrict__ bt, int total) {
    int i = blockIdx.x * 256 + threadIdx.x;
    if (i >= total) return;
    int z = i / (B_ * N);
    int c = i % N;
    int idx = z * N + c;
    float v = T[i];
    v = (v - meanb[idx]) * rstdb[idx] * g[idx] + bt[idx];
    T[i] = fmaxf(v, 0.f);
}

// ---------------- final sigmoid dot ----------------
__global__ void final_kernel(const float* __restrict__ T1, const float* __restrict__ tow,
                             const float* __restrict__ tob, float* __restrict__ out) {
    int r = blockIdx.x * 4 + (threadIdx.x >> 6);
    int lane = threadIdx.x & 63;
    int t = r >> 14;
    float v = T1[(size_t)r * 64 + lane] * tow[t * 64 + lane];
    #pragma unroll
    for (int off = 32; off > 0; off >>= 1) v += __shfl_xor(v, off);
    if (lane == 0) out[r] = 1.f / (1.f + expf(-(v + tob[t])));
}

extern "C" void kernel_launch(void* const* d_in, const int* in_sizes, int n_in,
                              void* d_out, int out_size, void* d_ws, size_t ws_size,
                              hipStream_t stream) {
    const int*   x    = (const int*)  d_in[0];
    const float* emb  = (const float*)d_in[1];
    const float* ew0  = (const float*)d_in[2];
    const float* eb0  = (const float*)d_in[3];
    const float* eg0  = (const float*)d_in[4];
    const float* ebt0 = (const float*)d_in[5];
    const float* gw0  = (const float*)d_in[6];
    const float* gb0  = (const float*)d_in[7];
    const float* ew1  = (const float*)d_in[10];
    const float* eb1  = (const float*)d_in[11];
    const float* eg1  = (const float*)d_in[12];
    const float* ebt1 = (const float*)d_in[13];
    const float* gw1  = (const float*)d_in[14];
    const float* gb1  = (const float*)d_in[15];
    const float* tw0  = (const float*)d_in[18];
    const float* tb0  = (const float*)d_in[19];
    const float* tg0  = (const float*)d_in[20];
    const float* tbt0 = (const float*)d_in[21];
    const float* tw1  = (const float*)d_in[22];
    const float* tb1  = (const float*)d_in[23];
    const float* tg1  = (const float*)d_in[24];
    const float* tbt1 = (const float*)d_in[25];
    const float* tow  = (const float*)d_in[26];
    const float* tob  = (const float*)d_in[27];
    float* out = (float*)d_out;

    // ---- workspace layout (float-granular offsets) ----
    float* ws = (float*)d_ws;
    size_t off = 0;
    u16* featH = (u16*)(ws + off);                       // B*1152 u16
    u16* featL = featH + (size_t)B_ * IN0_;
    u16* XH    = (u16*)(ws + off);                       // alias (feat dead before X written)
    u16* XL    = XH + (size_t)2 * B_ * 512;
    off += (size_t)B_ * IN0_;                            // covers both planes (u16)
    u16* W0H = (u16*)(ws + off); off += (size_t)12 * 1152 * 512 / 2;
    u16* W0L = (u16*)(ws + off); off += (size_t)12 * 1152 * 512 / 2;
    u16* W1H = (u16*)(ws + off); off += (size_t)12 * 512 * 256 / 2;
    u16* W1L = (u16*)(ws + off); off += (size_t)12 * 512 * 256 / 2;
    float* H      = ws + off; off += (size_t)12 * B_ * 512;   // reused: 16*B*256
    float* Y      = ws + off; off += (size_t)2 * B_ * 256;
    float* T0     = ws + off; off += (size_t)2 * B_ * 128;
    float* T1     = ws + off; off += (size_t)2 * B_ * 64;
    float* logits = ws + off; off += (size_t)B_ * 16;
    float* sumb   = ws + off; off += 8192;
    float* sumsqb = ws + off; off += 8192;
    float* meanb  = ws + off; off += 8192;
    float* rstdb  = ws + off; off += 8192;

    IMap idm, map_t0, map_t1, sl07, sl815, m01;
    for (int i = 0; i < 16; ++i) { idm.v[i] = i; sl07.v[i] = i; m01.v[i] = i & 1; }
    int a0[8] = {0,1,2,3,8,9,10,11}, a1[8] = {4,5,6,7,8,9,10,11};
    for (int i = 0; i < 8; ++i) { map_t0.v[i] = a0[i]; map_t1.v[i] = a1[i]; sl815.v[i] = 8 + i; }

    // 1) embedding gather -> split planes
    gather_kernel<<<(B_ * F_ * 16 + 255) / 256, 256, 0, stream>>>(x, emb, featH, featL);

    // 2) layer-0 weights: transpose + split
    wt_conv<<<dim3(512 / 32, 1152 / 32, 12), 256, 0, stream>>>(ew0, 1152, 512, W0H, W0L);

    // 3) layer 0: 12 expert GEMMs on MFMA (deduped across streams)
    gemm_mfma<<<dim3(512 / 128, B_ / 128, 12), 256, 0, stream>>>(featH, featL, 0,
                                                                 W0H, W0L, eb0, H, IN0_, 512, idm);
    hipMemsetAsync(sumb,   0, 12 * 512 * sizeof(float), stream);
    hipMemsetAsync(sumsqb, 0, 12 * 512 * sizeof(float), stream);
    bn_sum<<<dim3(2, 32, 12), 256, 0, stream>>>(H, 512, B_ / 32, sumb, sumsqb);
    bn_fin<<<(12 * 512 + 255) / 256, 256, 0, stream>>>(sumb, sumsqb, 12 * 512, meanb, rstdb);
    gate8<<<(2 * B_ + 255) / 256, 256, 0, stream>>>(featH, featL, 0, IN0_, gw0, gb0, logits);
    mix_kernel<<<B_, 256, 0, stream>>>(H, (long)B_ * 512, 512, logits, 0, meanb, rstdb,
                                       eg0, ebt0, map_t0, map_t0, nullptr, XH, XL);
    mix_kernel<<<B_, 256, 0, stream>>>(H, (long)B_ * 512, 512, logits, 1, meanb, rstdb,
                                       eg0, ebt0, map_t1, map_t1, nullptr,
                                       XH + (size_t)B_ * 512, XL + (size_t)B_ * 512);

    // 4) layer-1 weights: transpose + split
    wt_conv<<<dim3(256 / 32, 512 / 32, 12), 256, 0, stream>>>(ew1, 512, 256, W1H, W1L);

    // 5) layer 1: 16 expert GEMMs (shared stream pruned: output never consumed)
    gemm_mfma<<<dim3(256 / 128, B_ / 128, 8), 256, 0, stream>>>(XH, XL, 0, W1H, W1L, eb1,
                                                                H, 512, 256, map_t0);
    gemm_mfma<<<dim3(256 / 128, B_ / 128, 8), 256, 0, stream>>>(XH + (size_t)B_ * 512,
                                                                XL + (size_t)B_ * 512, 0,
                                                                W1H, W1L, eb1,
                                                                H + (size_t)8 * B_ * 256, 512, 256, map_t1);
    hipMemsetAsync(sumb,   0, 16 * 256 * sizeof(float), stream);
    hipMemsetAsync(sumsqb, 0, 16 * 256 * sizeof(float), stream);
    bn_sum<<<dim3(1, 32, 16), 256, 0, stream>>>(H, 256, B_ / 32, sumb, sumsqb);
    bn_fin<<<(16 * 256 + 255) / 256, 256, 0, stream>>>(sumb, sumsqb, 16 * 256, meanb, rstdb);
    gate8<<<(2 * B_ + 255) / 256, 256, 0, stream>>>(XH, XL, (long)B_ * 512, 512, gw1, gb1, logits);
    mix_kernel<<<B_, 256, 0, stream>>>(H, (long)B_ * 256, 256, logits, 0, meanb, rstdb,
                                       eg1, ebt1, sl07, map_t0, Y, nullptr, nullptr);
    mix_kernel<<<B_, 256, 0, stream>>>(H, (long)B_ * 256, 256, logits, 1, meanb, rstdb,
                                       eg1, ebt1, sl815, map_t1, Y + (size_t)B_ * 256, nullptr, nullptr);

    // 6) towers (fp32 vector GEMM; tiny FLOPs)
    gemm_bias128<<<dim3(1, B_ / 128, 2), 256, 0, stream>>>(Y, (long)B_ * 256, tw0, tb0, T0, 256, 128, m01);
    hipMemsetAsync(sumb,   0, 2 * 128 * sizeof(float), stream);
    hipMemsetAsync(sumsqb, 0, 2 * 128 * sizeof(float), stream);
    bn_sum<<<dim3(1, 32, 2), 256, 0, stream>>>(T0, 128, B_ / 32, sumb, sumsqb);
    bn_fin<<<1, 256, 0, stream>>>(sumb, sumsqb, 2 * 128, meanb, rstdb);
    bn_relu<<<(2 * B_ * 128 + 255) / 256, 256, 0, stream>>>(T0, 128, meanb, rstdb, tg0, tbt0, 2 * B_ * 128);

    gemm_bias<<<dim3(1, B_ / 64, 2), 256, 0, stream>>>(T0, (long)B_ * 128, tw1, tb1, T1, 128, 64, m01);
    hipMemsetAsync(sumb,   0, 2 * 64 * sizeof(float), stream);
    hipMemsetAsync(sumsqb, 0, 2 * 64 * sizeof(float), stream);
    bn_sum<<<dim3(1, 32, 2), 256, 0, stream>>>(T1, 64, B_ / 32, sumb, sumsqb);
    bn_fin<<<1, 256, 0, stream>>>(sumb, sumsqb, 2 * 64, meanb, rstdb);
    bn_relu<<<(2 * B_ * 64 + 255) / 256, 256, 0, stream>>>(T1, 64, meanb, rstdb, tg1, tbt1, 2 * B_ * 64);

    final_kernel<<<2 * B_ / 4, 256, 0, stream>>>(T1, tow, tob, out);
}